// Round 20
// baseline (185.393 us; speedup 1.0000x reference)
//
#include <hip/hip_runtime.h>
#include <cstdint>
#include <cstddef>

// DigitCapsule dynamic routing, fp32.
// x[256,1152,8], W[1152,10,16,8], out v[256,10,16].
// Design: lane = q*16 + d. vsum trick: logits at round r = votes.(v0+..+v_{r-1}).
// R20: votes MATERIALIZED once (188.7MB, Infinity-Cache-resident; working
// set 222MB < 256MB L3). capsV ran 3x at ~40us/pass while its arithmetic
// is worth ~5us (latency/codegen wall, R3-R19 ledger); now:
//   capsVW = R19 capsV<0> + in-loop raw-vote stores (votes + round-0 spart),
//   capsR (x2) = streaming reader: no LDS, no dots; 20 coalesced dword
//     reads/iter + R19's packed softmax. Loads are independent/streaming,
//     so the <=12-in-flight codegen wall doesn't bind.
// capsF unchanged from R19.
constexpr int Bn = 256, In = 1152, Pn = 8, Jn = 10, Dn = 16;
constexpr int CA = 8, NCH = In / CA;  // 144 chunks
constexpr int PADX = 18;              // x row pad: 16 used + 2 (bank spread)

typedef float v2f __attribute__((ext_vector_type(2)));

template <int CTRL>
__device__ __forceinline__ float dpp_add(float v) {
  const int s =
      __builtin_amdgcn_update_dpp(0, __float_as_int(v), CTRL, 0xf, 0xf, true);
  return v + __int_as_float(s);  // fuses to v_add_f32_dpp
}

// Sum over the 16 lanes of each row (lane&15 = d); every lane gets the sum.
// quad_perm xor1=0xB1, xor2=0x4E, row_ror:4=0x124, row_ror:8=0x128. Pure VALU.
__device__ __forceinline__ float rowsum16(float v) {
  v = dpp_add<0xB1>(v);
  v = dpp_add<0x4E>(v);
  v = dpp_add<0x124>(v);
  v = dpp_add<0x128>(v);
  return v;
}

// Packed dot over p: returns {sum of even p terms, sum of odd p terms}.
__device__ __forceinline__ v2f pkdot8(const float4 w0, const float4 w1,
                                      const float4 x0, const float4 x1) {
  v2f wa, wb, wc, wd, xa, xb, xc, xd;
  wa.x = w0.x; wa.y = w0.y; wb.x = w0.z; wb.y = w0.w;
  wc.x = w1.x; wc.y = w1.y; wd.x = w1.z; wd.y = w1.w;
  xa.x = x0.x; xa.y = x0.y; xb.x = x0.z; xb.y = x0.w;
  xc.x = x1.x; xc.y = x1.y; xd.x = x1.z; xd.y = x1.w;
  v2f acc = wa * xa;
  acc = __builtin_elementwise_fma(wb, xb, acc);
  acc = __builtin_elementwise_fma(wc, xc, acc);
  acc = __builtin_elementwise_fma(wd, xd, acc);
  return acc;
}

// capsVW: round 0 + votes materialization. thread: d = t&15, q = t>>4;
// b0 = blockIdx.y*32 + q, b1 = b0 + 16. block = (chunk, b-group of 32).
// LDS W (40KB) d-transposed; LDS x (9.2KB) padded - R19's proven staging.
// Per (i,j): compute vt2 (packed dots), STORE raw votes (coalesced 1KB
// runs per wave: [i][j][bbase+q][d]), accumulate acc += vt2; epilogue
// writes spart * 0.1 (softmax of zero logits = 0.1 exactly).
__global__ __launch_bounds__(256)
__attribute__((amdgpu_waves_per_eu(3, 4)))
void capsVW(const float* __restrict__ x, const float* __restrict__ w,
            float* __restrict__ votes, float* __restrict__ spart) {
  __shared__ float4 wlds[CA * Jn * 2 * 16];  // 2560 units = 40 KB
  __shared__ float4 xlds[32 * PADX];         // 9.2 KB
  const int t = threadIdx.x;
  const int d = t & 15, q = t >> 4;
  const int ch = blockIdx.x;
  const int bbase = blockIdx.y * 32;
  const int b0 = bbase + q, b1 = b0 + 16;
  const int i0 = ch * CA;

  // ---- stage W chunk: 2560 units / 256 threads = 10 each (coalesced) ----
  {
    const float4* wg =
        reinterpret_cast<const float4*>(w + (size_t)i0 * (Jn * Dn * Pn));
    for (int k = 0; k < 10; ++k) {
      const int g = t + k * 256;
      const int h = g & 1, dd = (g >> 1) & 15, ij = g >> 5;
      wlds[(ij * 2 + h) * 16 + dd] = wg[g];
    }
  }
  // ---- stage x chunk: 32 b's x 16 float4 = 512 units, 2 per thread ----
  {
    for (int k = 0; k < 2; ++k) {
      const int u = t + k * 256;
      const int bl = u >> 4, idx = u & 15;
      xlds[bl * PADX + idx] = reinterpret_cast<const float4*>(
          x + ((size_t)(bbase + bl) * In + i0) * Pn)[idx];
    }
  }

  v2f acc2[Jn];
  #pragma unroll
  for (int j = 0; j < Jn; ++j) acc2[j] = (v2f)(0.f);

  __syncthreads();  // staged W and x visible to all waves

  for (int ii = 0; ii < CA; ++ii) {
    const float4 xa0 = xlds[q * PADX + ii * 2];
    const float4 xa1 = xlds[q * PADX + ii * 2 + 1];
    const float4 xb0 = xlds[(q + 16) * PADX + ii * 2];
    const float4 xb1 = xlds[(q + 16) * PADX + ii * 2 + 1];

    float* vrow = votes + ((size_t)(i0 + ii) * Jn) * (Bn * Dn) + d;
    #pragma unroll
    for (int j = 0; j < Jn; ++j) {
      const float4* wrow = &wlds[((ii * Jn + j) * 2) * 16 + d];
      const float4 w0 = wrow[0];   // h=0
      const float4 w1 = wrow[16];  // h=1
      const v2f pa = pkdot8(w0, w1, xa0, xa1);  // b0 even/odd halves
      const v2f pb = pkdot8(w0, w1, xb0, xb1);  // b1
      v2f vt;
      vt.x = pa.x + pa.y;
      vt.y = pb.x + pb.y;
      vrow[(size_t)j * (Bn * Dn) + b0 * Dn] = vt.x;  // raw votes
      vrow[(size_t)j * (Bn * Dn) + b1 * Dn] = vt.y;
      acc2[j] += vt;  // pk_add
    }
  }

  #pragma unroll
  for (int j = 0; j < Jn; ++j) {
    spart[(((size_t)ch * Jn + j) * Bn + b0) * Dn + d] = acc2[j].x * 0.1f;
    spart[(((size_t)ch * Jn + j) * Bn + b1) * Dn + d] = acc2[j].y * 0.1f;
  }
}

// capsR: one routing round from materialized votes. No LDS, no dots.
// thread: d = t&15, q = t>>4; b0 = blockIdx.y*32 + q, b1 = b0 + 16.
// block = (chunk, b-group of 32). Per (i,j): 2 coalesced dword reads of
// votes (wave covers 1KB contiguous per half), then R19's packed softmax
// (logits via DPP rowsum16, no max-sub: logits O(0.1)) and acc.
__global__ __launch_bounds__(256)
__attribute__((amdgpu_waves_per_eu(3, 4)))
void capsR(const float* __restrict__ votes, const float* __restrict__ vsumT,
           float* __restrict__ spart) {
  const int t = threadIdx.x;
  const int d = t & 15, q = t >> 4;
  const int ch = blockIdx.x;
  const int bbase = blockIdx.y * 32;
  const int b0 = bbase + q, b1 = b0 + 16;
  const int i0 = ch * CA;

  v2f vs2[Jn], acc2[Jn];
  #pragma unroll
  for (int j = 0; j < Jn; ++j) {
    acc2[j] = (v2f)(0.f);
    vs2[j].x = vsumT[((size_t)j * Bn + b0) * Dn + d];
    vs2[j].y = vsumT[((size_t)j * Bn + b1) * Dn + d];
  }

  for (int ii = 0; ii < CA; ++ii) {
    const float* vrow = votes + ((size_t)(i0 + ii) * Jn) * (Bn * Dn) + d;

    v2f vt2[Jn];
    #pragma unroll
    for (int j = 0; j < Jn; ++j) {
      vt2[j].x = vrow[(size_t)j * (Bn * Dn) + b0 * Dn];
      vt2[j].y = vrow[(size_t)j * (Bn * Dn) + b1 * Dn];
    }

    v2f e2[Jn], sum2 = (v2f)(0.f);
    #pragma unroll
    for (int j = 0; j < Jn; ++j) {
      const v2f lp = vt2[j] * vs2[j];  // pk_mul
      e2[j].x = __expf(rowsum16(lp.x));
      e2[j].y = __expf(rowsum16(lp.y));
      sum2 += e2[j];  // pk_add
    }
    v2f inv2;
    inv2.x = __builtin_amdgcn_rcpf(sum2.x);
    inv2.y = __builtin_amdgcn_rcpf(sum2.y);
    #pragma unroll
    for (int j = 0; j < Jn; ++j)
      acc2[j] = __builtin_elementwise_fma(e2[j] * inv2, vt2[j], acc2[j]);
  }

  #pragma unroll
  for (int j = 0; j < Jn; ++j) {
    spart[(((size_t)ch * Jn + j) * Bn + b0) * Dn + d] = acc2[j].x;
    spart[(((size_t)ch * Jn + j) * Bn + b1) * Dn + d] = acc2[j].y;
  }
}

// capsF: reduce 144 chunk-partials, squash. 1024 threads: 8 chunk-groups
// (cg = t>>7) each privately sum 18 chunks for an 8b x 16d slab; LDS
// combine across cg; squash norm via DPP rowsum16 in the t<128 tail.
// block = (j, b-group of 8), grid (10, 32).
// MODE 0: vsumT = v ; MODE 1: vsumT += v ; MODE 2: out[b][j][d] = v.
template <int MODE>
__global__ __launch_bounds__(1024) void capsF(
    const float* __restrict__ spart, float* __restrict__ vsumT,
    float* __restrict__ out) {
  __shared__ float red[8][8][16];
  const int t = threadIdx.x;
  const int cg = t >> 7, r = t & 127, g = r >> 4, d = r & 15;
  const int j = blockIdx.x, b = blockIdx.y * 8 + g;

  const size_t cstride = (size_t)Jn * Bn * Dn;  // one chunk, in floats
  const size_t cstep = 8 * cstride;             // stride between my chunks
  const float* sp = spart + (((size_t)cg * Jn + j) * Bn + b) * Dn + d;
  float s0 = 0.f, s1 = 0.f;
  #pragma unroll 3
  for (int k = 0; k < NCH / 8; k += 2) {
    s0 += sp[0];
    s1 += sp[cstep];
    sp += 2 * cstep;
  }
  red[cg][g][d] = s0 + s1;
  __syncthreads();
  if (t < 128) {
    float z = 0.f;
    #pragma unroll
    for (int c = 0; c < 8; ++c) z += red[c][g][d];
    const float n2 = rowsum16(z * z);
    const float sc = n2 / (1.f + n2) / sqrtf(n2 + 1e-7f);
    const float v = z * sc;
    if (MODE == 2) {
      out[((size_t)b * Jn + j) * Dn + d] = v;
    } else if (MODE == 1) {
      vsumT[((size_t)j * Bn + b) * Dn + d] += v;
    } else {
      vsumT[((size_t)j * Bn + b) * Dn + d] = v;
    }
  }
}

extern "C" void kernel_launch(void* const* d_in, const int* in_sizes, int n_in,
                              void* d_out, int out_size, void* d_ws, size_t ws_size,
                              hipStream_t stream) {
  const float* x = (const float*)d_in[0];  // [256,1152,8]
  const float* w = (const float*)d_in[1];  // [1152,10,16,8]
  float* vsumT = (float*)d_ws;                      // [J][B][D]     0.16 MB
  float* spart = vsumT + (size_t)Jn * Bn * Dn;      // [NCH][J][B][D] 23.6 MB
  float* votes = spart + (size_t)NCH * Jn * Bn * Dn;// [I][J][B][D]  188.7 MB
  float* out = (float*)d_out;                       // [256,10,16]

  const dim3 gV(NCH, Bn / 32), gF(Jn, Bn / 8);

  capsVW<<<gV, 256, 0, stream>>>(x, w, votes, spart);     // votes + round 0
  capsF<0><<<gF, 1024, 0, stream>>>(spart, vsumT, out);   // vsum = v0

  capsR<<<gV, 256, 0, stream>>>(votes, vsumT, spart);     // round 1
  capsF<1><<<gF, 1024, 0, stream>>>(spart, vsumT, out);   // vsum += v1

  capsR<<<gV, 256, 0, stream>>>(votes, vsumT, spart);     // round 2
  capsF<2><<<gF, 1024, 0, stream>>>(spart, vsumT, out);   // out = v2
}

// Round 21
// 154.720 us; speedup vs baseline: 1.1982x; 1.1982x over previous
//
#include <hip/hip_runtime.h>
#include <cstdint>
#include <cstddef>

// DigitCapsule dynamic routing, fp32.
// x[256,1152,8], W[1152,10,16,8], out v[256,10,16].
// Design: lane = q*16 + d. vsum trick: logits at round r = votes.(v0+..+v_{r-1}).
// R21 = exact revert to R19 (best: 157.1us). R20's votes-materialization
// regressed (207MB votes stream went to HBM, not L3: WRITE_SIZE 207MB at
// 5.2TB/s on capsVW). Final structure:
//   capsV: W+x staged in LDS (49KB), zero-VMEM inner loop, packed v_pk
//     fp32 dots/softmax, DPP rowsum16, attr(3,4) -> VGPR-84 groove, CA=8.
//   capsF: 8-group LDS reduction + DPP squash.
// Session ledger: capsV's ~40us is a dependent-chain latency wall bracketed
// by 8 lever families (occupancy x4, VMEM removal, LDS-pipe offload,
// packing, batching, atomics, materialization) - no pipe saturated, every
// exit measured shut.
constexpr int Bn = 256, In = 1152, Pn = 8, Jn = 10, Dn = 16;
constexpr int CA = 8, NCH = In / CA;  // 144 chunks
constexpr int PADX = 18;              // x row pad: 16 used + 2 (bank spread)

typedef float v2f __attribute__((ext_vector_type(2)));

template <int CTRL>
__device__ __forceinline__ float dpp_add(float v) {
  const int s =
      __builtin_amdgcn_update_dpp(0, __float_as_int(v), CTRL, 0xf, 0xf, true);
  return v + __int_as_float(s);  // fuses to v_add_f32_dpp
}

// Sum over the 16 lanes of each row (lane&15 = d); every lane gets the sum.
// quad_perm xor1=0xB1, xor2=0x4E, row_ror:4=0x124, row_ror:8=0x128. Pure VALU.
__device__ __forceinline__ float rowsum16(float v) {
  v = dpp_add<0xB1>(v);
  v = dpp_add<0x4E>(v);
  v = dpp_add<0x124>(v);
  v = dpp_add<0x128>(v);
  return v;
}

// Packed dot over p: returns {sum of even p terms, sum of odd p terms}.
// 1 pk_mul + 3 pk_fma; caller adds the two halves (1 scalar add).
__device__ __forceinline__ v2f pkdot8(const float4 w0, const float4 w1,
                                      const float4 x0, const float4 x1) {
  v2f wa, wb, wc, wd, xa, xb, xc, xd;
  wa.x = w0.x; wa.y = w0.y; wb.x = w0.z; wb.y = w0.w;
  wc.x = w1.x; wc.y = w1.y; wd.x = w1.z; wd.y = w1.w;
  xa.x = x0.x; xa.y = x0.y; xb.x = x0.z; xb.y = x0.w;
  xc.x = x1.x; xc.y = x1.y; xd.x = x1.z; xd.y = x1.w;
  v2f acc = wa * xa;
  acc = __builtin_elementwise_fma(wb, xb, acc);
  acc = __builtin_elementwise_fma(wc, xc, acc);
  acc = __builtin_elementwise_fma(wd, xd, acc);
  return acc;
}

// capsV: one routing round's weighted vote sum over an i-chunk, 2 b's/thread.
// thread: d = t&15, q = t>>4; b0 = blockIdx.y*32 + q, b1 = b0 + 16.
// block = (chunk, b-group of 32).
// LDS W (40KB): 16B units, unit = ((ii*Jn+j)*2+h)*16 + d (d-transposed:
//   lane d's b128 read -> 2-way bank alias, free; q-groups broadcast).
// LDS x (9.2KB): [32 b][PADX float4], 16 used + 2 pad.
// Packed state: vt2/vs2/acc2/e2[j] = {b0, b1} in one v2f.
// MODE 0: softmax of zero logits = 0.1 exactly -> raw vote sum * 0.1.
template <int MODE>
__global__ __launch_bounds__(256)
__attribute__((amdgpu_waves_per_eu(3, 4)))
void capsV(const float* __restrict__ x, const float* __restrict__ w,
           const float* __restrict__ vsumT, float* __restrict__ spart) {
  __shared__ float4 wlds[CA * Jn * 2 * 16];  // 2560 units = 40 KB
  __shared__ float4 xlds[32 * PADX];         // 9.2 KB
  const int t = threadIdx.x;
  const int d = t & 15, q = t >> 4;
  const int ch = blockIdx.x;
  const int bbase = blockIdx.y * 32;
  const int b0 = bbase + q, b1 = b0 + 16;
  const int i0 = ch * CA;

  // ---- stage W chunk: 2560 units / 256 threads = 10 each (coalesced) ----
  {
    const float4* wg =
        reinterpret_cast<const float4*>(w + (size_t)i0 * (Jn * Dn * Pn));
    for (int k = 0; k < 10; ++k) {
      const int g = t + k * 256;
      const int h = g & 1, dd = (g >> 1) & 15, ij = g >> 5;
      wlds[(ij * 2 + h) * 16 + dd] = wg[g];
    }
  }
  // ---- stage x chunk: 32 b's x 16 float4 = 512 units, 2 per thread ----
  {
    for (int k = 0; k < 2; ++k) {
      const int u = t + k * 256;
      const int bl = u >> 4, idx = u & 15;
      xlds[bl * PADX + idx] = reinterpret_cast<const float4*>(
          x + ((size_t)(bbase + bl) * In + i0) * Pn)[idx];
    }
  }

  v2f vs2[Jn], acc2[Jn];
  #pragma unroll
  for (int j = 0; j < Jn; ++j) {
    acc2[j] = (v2f)(0.f);
    if (MODE) {
      vs2[j].x = vsumT[((size_t)j * Bn + b0) * Dn + d];
      vs2[j].y = vsumT[((size_t)j * Bn + b1) * Dn + d];
    }
  }

  __syncthreads();  // staged W and x visible to all waves

  for (int ii = 0; ii < CA; ++ii) {
    const float4 xa0 = xlds[q * PADX + ii * 2];
    const float4 xa1 = xlds[q * PADX + ii * 2 + 1];
    const float4 xb0 = xlds[(q + 16) * PADX + ii * 2];
    const float4 xb1 = xlds[(q + 16) * PADX + ii * 2 + 1];

    v2f vt2[Jn];
    #pragma unroll
    for (int j = 0; j < Jn; ++j) {
      const float4* wrow = &wlds[((ii * Jn + j) * 2) * 16 + d];
      const float4 w0 = wrow[0];   // h=0
      const float4 w1 = wrow[16];  // h=1
      const v2f pa = pkdot8(w0, w1, xa0, xa1);  // b0 even/odd halves
      const v2f pb = pkdot8(w0, w1, xb0, xb1);  // b1
      vt2[j].x = pa.x + pa.y;
      vt2[j].y = pb.x + pb.y;
    }

    if (MODE) {
      v2f e2[Jn], sum2 = (v2f)(0.f);
      #pragma unroll
      for (int j = 0; j < Jn; ++j) {
        const v2f lp = vt2[j] * vs2[j];  // pk_mul
        // logits O(0.1): no max-subtraction needed.
        e2[j].x = __expf(rowsum16(lp.x));
        e2[j].y = __expf(rowsum16(lp.y));
        sum2 += e2[j];  // pk_add
      }
      v2f inv2;
      inv2.x = __builtin_amdgcn_rcpf(sum2.x);
      inv2.y = __builtin_amdgcn_rcpf(sum2.y);
      #pragma unroll
      for (int j = 0; j < Jn; ++j)
        acc2[j] = __builtin_elementwise_fma(e2[j] * inv2, vt2[j], acc2[j]);
    } else {
      #pragma unroll
      for (int j = 0; j < Jn; ++j) acc2[j] += vt2[j];  // pk_add
    }
  }

  const float cs = MODE ? 1.f : 0.1f;
  #pragma unroll
  for (int j = 0; j < Jn; ++j) {
    spart[(((size_t)ch * Jn + j) * Bn + b0) * Dn + d] = acc2[j].x * cs;
    spart[(((size_t)ch * Jn + j) * Bn + b1) * Dn + d] = acc2[j].y * cs;
  }
}

// capsF: reduce 144 chunk-partials, squash. 1024 threads: 8 chunk-groups
// (cg = t>>7) each privately sum 18 chunks for an 8b x 16d slab; LDS
// combine across cg; squash norm via DPP rowsum16 in the t<128 tail.
// block = (j, b-group of 8), grid (10, 32).
// MODE 0: vsumT = v ; MODE 1: vsumT += v ; MODE 2: out[b][j][d] = v.
template <int MODE>
__global__ __launch_bounds__(1024) void capsF(
    const float* __restrict__ spart, float* __restrict__ vsumT,
    float* __restrict__ out) {
  __shared__ float red[8][8][16];
  const int t = threadIdx.x;
  const int cg = t >> 7, r = t & 127, g = r >> 4, d = r & 15;
  const int j = blockIdx.x, b = blockIdx.y * 8 + g;

  const size_t cstride = (size_t)Jn * Bn * Dn;  // one chunk, in floats
  const size_t cstep = 8 * cstride;             // stride between my chunks
  const float* sp = spart + (((size_t)cg * Jn + j) * Bn + b) * Dn + d;
  float s0 = 0.f, s1 = 0.f;
  #pragma unroll 3
  for (int k = 0; k < NCH / 8; k += 2) {
    s0 += sp[0];
    s1 += sp[cstep];
    sp += 2 * cstep;
  }
  red[cg][g][d] = s0 + s1;
  __syncthreads();
  if (t < 128) {
    float z = 0.f;
    #pragma unroll
    for (int c = 0; c < 8; ++c) z += red[c][g][d];
    const float n2 = rowsum16(z * z);
    const float sc = n2 / (1.f + n2) / sqrtf(n2 + 1e-7f);
    const float v = z * sc;
    if (MODE == 2) {
      out[((size_t)b * Jn + j) * Dn + d] = v;
    } else if (MODE == 1) {
      vsumT[((size_t)j * Bn + b) * Dn + d] += v;
    } else {
      vsumT[((size_t)j * Bn + b) * Dn + d] = v;
    }
  }
}

extern "C" void kernel_launch(void* const* d_in, const int* in_sizes, int n_in,
                              void* d_out, int out_size, void* d_ws, size_t ws_size,
                              hipStream_t stream) {
  const float* x = (const float*)d_in[0];  // [256,1152,8]
  const float* w = (const float*)d_in[1];  // [1152,10,16,8]
  float* vsumT = (float*)d_ws;                      // [J][B][D]   0.16 MB
  float* spart = vsumT + (size_t)Jn * Bn * Dn;      // [NCH][J][B][D] 23.6 MB
  float* out = (float*)d_out;                       // [256,10,16]

  const dim3 gV(NCH, Bn / 32), gF(Jn, Bn / 8);

  capsV<0><<<gV, 256, 0, stream>>>(x, w, nullptr, spart);
  capsF<0><<<gF, 1024, 0, stream>>>(spart, vsumT, out);   // vsum = v0

  capsV<1><<<gV, 256, 0, stream>>>(x, w, vsumT, spart);   // round 1
  capsF<1><<<gF, 1024, 0, stream>>>(spart, vsumT, out);   // vsum += v1

  capsV<1><<<gV, 256, 0, stream>>>(x, w, vsumT, spart);   // round 2
  capsF<2><<<gF, 1024, 0, stream>>>(spart, vsumT, out);   // out = v2
}

// Round 22
// 153.488 us; speedup vs baseline: 1.2079x; 1.0080x over previous
//
#include <hip/hip_runtime.h>
#include <cstdint>
#include <cstddef>

// DigitCapsule dynamic routing, fp32.
// x[256,1152,8], W[1152,10,16,8], out v[256,10,16].
// Design: lane = q*16 + d. vsum trick: logits at round r = votes.(v0+..+v_{r-1}).
// R22 = R21/R19 (best, 154.7us: W+x in LDS, zero-VMEM inner loop, packed
// v_pk fp32, DPP rowsum16, attr(3,4) VGPR-84 groove, CA=8) + exp2 fold:
// __expf(x) = v_mul(x,log2e) + v_exp_f32; fold log2e into vs2 ONCE at load
// (20 muls/kernel instead of 20 muls/iter) and call native exp2 directly.
// Saves ~8% of MODE-1 VALU slots with zero structural perturbation.
// Session ledger: capsV's ~40us is a dependent-chain latency wall bracketed
// by 8 lever families; dispatch gaps ~33us are the algorithmic minimum.
constexpr int Bn = 256, In = 1152, Pn = 8, Jn = 10, Dn = 16;
constexpr int CA = 8, NCH = In / CA;  // 144 chunks
constexpr int PADX = 18;              // x row pad: 16 used + 2 (bank spread)
constexpr float LOG2E = 1.4426950408889634f;

typedef float v2f __attribute__((ext_vector_type(2)));

#if defined(__has_builtin)
#if __has_builtin(__builtin_amdgcn_exp2f)
#define EXP2F(xx) __builtin_amdgcn_exp2f(xx)
#endif
#endif
#ifndef EXP2F
extern "C" __device__ float __ocml_native_exp2_f32(float);
#define EXP2F(xx) __ocml_native_exp2_f32(xx)
#endif

template <int CTRL>
__device__ __forceinline__ float dpp_add(float v) {
  const int s =
      __builtin_amdgcn_update_dpp(0, __float_as_int(v), CTRL, 0xf, 0xf, true);
  return v + __int_as_float(s);  // fuses to v_add_f32_dpp
}

// Sum over the 16 lanes of each row (lane&15 = d); every lane gets the sum.
// quad_perm xor1=0xB1, xor2=0x4E, row_ror:4=0x124, row_ror:8=0x128. Pure VALU.
__device__ __forceinline__ float rowsum16(float v) {
  v = dpp_add<0xB1>(v);
  v = dpp_add<0x4E>(v);
  v = dpp_add<0x124>(v);
  v = dpp_add<0x128>(v);
  return v;
}

// Packed dot over p: returns {sum of even p terms, sum of odd p terms}.
// 1 pk_mul + 3 pk_fma; caller adds the two halves (1 scalar add).
__device__ __forceinline__ v2f pkdot8(const float4 w0, const float4 w1,
                                      const float4 x0, const float4 x1) {
  v2f wa, wb, wc, wd, xa, xb, xc, xd;
  wa.x = w0.x; wa.y = w0.y; wb.x = w0.z; wb.y = w0.w;
  wc.x = w1.x; wc.y = w1.y; wd.x = w1.z; wd.y = w1.w;
  xa.x = x0.x; xa.y = x0.y; xb.x = x0.z; xb.y = x0.w;
  xc.x = x1.x; xc.y = x1.y; xd.x = x1.z; xd.y = x1.w;
  v2f acc = wa * xa;
  acc = __builtin_elementwise_fma(wb, xb, acc);
  acc = __builtin_elementwise_fma(wc, xc, acc);
  acc = __builtin_elementwise_fma(wd, xd, acc);
  return acc;
}

// capsV: one routing round's weighted vote sum over an i-chunk, 2 b's/thread.
// thread: d = t&15, q = t>>4; b0 = blockIdx.y*32 + q, b1 = b0 + 16.
// block = (chunk, b-group of 32).
// LDS W (40KB): 16B units, unit = ((ii*Jn+j)*2+h)*16 + d (d-transposed:
//   lane d's b128 read -> 2-way bank alias, free; q-groups broadcast).
// LDS x (9.2KB): [32 b][PADX float4], 16 used + 2 pad.
// Packed state: vt2/vs2/acc2/e2[j] = {b0, b1} in one v2f; vs2 pre-scaled
//   by LOG2E so softmax exp is a single native v_exp_f32 (base-2).
// MODE 0: softmax of zero logits = 0.1 exactly -> raw vote sum * 0.1.
template <int MODE>
__global__ __launch_bounds__(256)
__attribute__((amdgpu_waves_per_eu(3, 4)))
void capsV(const float* __restrict__ x, const float* __restrict__ w,
           const float* __restrict__ vsumT, float* __restrict__ spart) {
  __shared__ float4 wlds[CA * Jn * 2 * 16];  // 2560 units = 40 KB
  __shared__ float4 xlds[32 * PADX];         // 9.2 KB
  const int t = threadIdx.x;
  const int d = t & 15, q = t >> 4;
  const int ch = blockIdx.x;
  const int bbase = blockIdx.y * 32;
  const int b0 = bbase + q, b1 = b0 + 16;
  const int i0 = ch * CA;

  // ---- stage W chunk: 2560 units / 256 threads = 10 each (coalesced) ----
  {
    const float4* wg =
        reinterpret_cast<const float4*>(w + (size_t)i0 * (Jn * Dn * Pn));
    for (int k = 0; k < 10; ++k) {
      const int g = t + k * 256;
      const int h = g & 1, dd = (g >> 1) & 15, ij = g >> 5;
      wlds[(ij * 2 + h) * 16 + dd] = wg[g];
    }
  }
  // ---- stage x chunk: 32 b's x 16 float4 = 512 units, 2 per thread ----
  {
    for (int k = 0; k < 2; ++k) {
      const int u = t + k * 256;
      const int bl = u >> 4, idx = u & 15;
      xlds[bl * PADX + idx] = reinterpret_cast<const float4*>(
          x + ((size_t)(bbase + bl) * In + i0) * Pn)[idx];
    }
  }

  v2f vs2[Jn], acc2[Jn];
  #pragma unroll
  for (int j = 0; j < Jn; ++j) {
    acc2[j] = (v2f)(0.f);
    if (MODE) {
      // Pre-scale by LOG2E: logits land in log2 domain, exp = native exp2.
      vs2[j].x = vsumT[((size_t)j * Bn + b0) * Dn + d] * LOG2E;
      vs2[j].y = vsumT[((size_t)j * Bn + b1) * Dn + d] * LOG2E;
    }
  }

  __syncthreads();  // staged W and x visible to all waves

  for (int ii = 0; ii < CA; ++ii) {
    const float4 xa0 = xlds[q * PADX + ii * 2];
    const float4 xa1 = xlds[q * PADX + ii * 2 + 1];
    const float4 xb0 = xlds[(q + 16) * PADX + ii * 2];
    const float4 xb1 = xlds[(q + 16) * PADX + ii * 2 + 1];

    v2f vt2[Jn];
    #pragma unroll
    for (int j = 0; j < Jn; ++j) {
      const float4* wrow = &wlds[((ii * Jn + j) * 2) * 16 + d];
      const float4 w0 = wrow[0];   // h=0
      const float4 w1 = wrow[16];  // h=1
      const v2f pa = pkdot8(w0, w1, xa0, xa1);  // b0 even/odd halves
      const v2f pb = pkdot8(w0, w1, xb0, xb1);  // b1
      vt2[j].x = pa.x + pa.y;
      vt2[j].y = pb.x + pb.y;
    }

    if (MODE) {
      v2f e2[Jn], sum2 = (v2f)(0.f);
      #pragma unroll
      for (int j = 0; j < Jn; ++j) {
        const v2f lp = vt2[j] * vs2[j];  // pk_mul, log2-domain logit parts
        // logits O(0.1): no max-subtraction needed.
        e2[j].x = EXP2F(rowsum16(lp.x));
        e2[j].y = EXP2F(rowsum16(lp.y));
        sum2 += e2[j];  // pk_add
      }
      v2f inv2;
      inv2.x = __builtin_amdgcn_rcpf(sum2.x);
      inv2.y = __builtin_amdgcn_rcpf(sum2.y);
      #pragma unroll
      for (int j = 0; j < Jn; ++j)
        acc2[j] = __builtin_elementwise_fma(e2[j] * inv2, vt2[j], acc2[j]);
    } else {
      #pragma unroll
      for (int j = 0; j < Jn; ++j) acc2[j] += vt2[j];  // pk_add
    }
  }

  const float cs = MODE ? 1.f : 0.1f;
  #pragma unroll
  for (int j = 0; j < Jn; ++j) {
    spart[(((size_t)ch * Jn + j) * Bn + b0) * Dn + d] = acc2[j].x * cs;
    spart[(((size_t)ch * Jn + j) * Bn + b1) * Dn + d] = acc2[j].y * cs;
  }
}

// capsF: reduce 144 chunk-partials, squash. 1024 threads: 8 chunk-groups
// (cg = t>>7) each privately sum 18 chunks for an 8b x 16d slab; LDS
// combine across cg; squash norm via DPP rowsum16 in the t<128 tail.
// block = (j, b-group of 8), grid (10, 32).
// MODE 0: vsumT = v ; MODE 1: vsumT += v ; MODE 2: out[b][j][d] = v.
template <int MODE>
__global__ __launch_bounds__(1024) void capsF(
    const float* __restrict__ spart, float* __restrict__ vsumT,
    float* __restrict__ out) {
  __shared__ float red[8][8][16];
  const int t = threadIdx.x;
  const int cg = t >> 7, r = t & 127, g = r >> 4, d = r & 15;
  const int j = blockIdx.x, b = blockIdx.y * 8 + g;

  const size_t cstride = (size_t)Jn * Bn * Dn;  // one chunk, in floats
  const size_t cstep = 8 * cstride;             // stride between my chunks
  const float* sp = spart + (((size_t)cg * Jn + j) * Bn + b) * Dn + d;
  float s0 = 0.f, s1 = 0.f;
  #pragma unroll 3
  for (int k = 0; k < NCH / 8; k += 2) {
    s0 += sp[0];
    s1 += sp[cstep];
    sp += 2 * cstep;
  }
  red[cg][g][d] = s0 + s1;
  __syncthreads();
  if (t < 128) {
    float z = 0.f;
    #pragma unroll
    for (int c = 0; c < 8; ++c) z += red[c][g][d];
    const float n2 = rowsum16(z * z);
    const float sc = n2 / (1.f + n2) / sqrtf(n2 + 1e-7f);
    const float v = z * sc;
    if (MODE == 2) {
      out[((size_t)b * Jn + j) * Dn + d] = v;
    } else if (MODE == 1) {
      vsumT[((size_t)j * Bn + b) * Dn + d] += v;
    } else {
      vsumT[((size_t)j * Bn + b) * Dn + d] = v;
    }
  }
}

extern "C" void kernel_launch(void* const* d_in, const int* in_sizes, int n_in,
                              void* d_out, int out_size, void* d_ws, size_t ws_size,
                              hipStream_t stream) {
  const float* x = (const float*)d_in[0];  // [256,1152,8]
  const float* w = (const float*)d_in[1];  // [1152,10,16,8]
  float* vsumT = (float*)d_ws;                      // [J][B][D]   0.16 MB
  float* spart = vsumT + (size_t)Jn * Bn * Dn;      // [NCH][J][B][D] 23.6 MB
  float* out = (float*)d_out;                       // [256,10,16]

  const dim3 gV(NCH, Bn / 32), gF(Jn, Bn / 8);

  capsV<0><<<gV, 256, 0, stream>>>(x, w, nullptr, spart);
  capsF<0><<<gF, 1024, 0, stream>>>(spart, vsumT, out);   // vsum = v0

  capsV<1><<<gV, 256, 0, stream>>>(x, w, vsumT, spart);   // round 1
  capsF<1><<<gF, 1024, 0, stream>>>(spart, vsumT, out);   // vsum += v1

  capsV<1><<<gV, 256, 0, stream>>>(x, w, vsumT, spart);   // round 2
  capsF<2><<<gF, 1024, 0, stream>>>(spart, vsumT, out);   // out = v2
}